// Round 2
// baseline (4277.203 us; speedup 1.0000x reference)
//
#include <hip/hip_runtime.h>
#include <hip/hip_bf16.h>

typedef __bf16 bf16;
typedef __bf16 bf16x8 __attribute__((ext_vector_type(8)));
typedef float f32x4 __attribute__((ext_vector_type(4)));

// ---------------------------------------------------------------------------
// Weight conversion fp32 -> bf16, and combined bias bih+bhh
// Wih: 2*2048*512 ; Whh: 2*2048*512 ; decW: 512*512 ; bias: 2*2048
// ---------------------------------------------------------------------------
__global__ void convert_w(const float* __restrict__ Wih, const float* __restrict__ Whh,
                          const float* __restrict__ decW, const float* __restrict__ bih,
                          const float* __restrict__ bhh,
                          bf16* __restrict__ WihB, bf16* __restrict__ WhhB,
                          bf16* __restrict__ decWB, float* __restrict__ bias) {
    int idx = blockIdx.x * 256 + threadIdx.x;
    const int NW = 2 * 2048 * 512;           // 2097152 (both layers)
    if (idx < NW) {
        WihB[idx] = (bf16)Wih[idx];
    } else if (idx < 2 * NW) {
        WhhB[idx - NW] = (bf16)Whh[idx - NW];
    } else if (idx < 2 * NW + 512 * 512) {
        decWB[idx - 2 * NW] = (bf16)decW[idx - 2 * NW];
    } else if (idx < 2 * NW + 512 * 512 + 4096) {
        int j = idx - (2 * NW + 512 * 512);
        bias[j] = bih[j] + bhh[j];
    }
}

// ---------------------------------------------------------------------------
// inp[b,t,h] = emb[trg[b,t], h] + y[b]*yW[h] + yb[h]   (bf16 out)
// trg[b,0] = 512 (start token), trg[b,t] = x[b,t-1]
// ---------------------------------------------------------------------------
__global__ void prep_inp(const int* __restrict__ x, const float* __restrict__ y,
                         const float* __restrict__ emb, const float* __restrict__ yW,
                         const float* __restrict__ yb, bf16* __restrict__ inp) {
    int idx = blockIdx.x * 256 + threadIdx.x;   // total 65536*64
    int bt = idx >> 6;
    int h0 = (idx & 63) * 8;
    int b = bt >> 7, t = bt & 127;
    int trg = (t == 0) ? 512 : x[b * 128 + t - 1];
    float yv = y[b];
    const float* e = emb + (size_t)trg * 512 + h0;
    bf16x8 v;
    #pragma unroll
    for (int i = 0; i < 8; ++i) v[i] = (bf16)(e[i] + yv * yW[h0 + i] + yb[h0 + i]);
    *(bf16x8*)&inp[(size_t)bt * 512 + h0] = v;
}

// ---------------------------------------------------------------------------
// C[M,N] = A[M,512] * W[N,512]^T + bias[N]
// 128x128 block tile, 4 waves (2x2 of 64x64), 16x16x32 bf16 MFMA, BK=32.
// LDS row stride 40 bf16 (80B): keeps every ds_read_b128 16B-aligned and
// gives a 2-way (free) bank pattern.
// ---------------------------------------------------------------------------
template <bool OUT_BF16>
__global__ __launch_bounds__(256) void gemm_bt(const bf16* __restrict__ A,
                                               const bf16* __restrict__ W,
                                               const float* __restrict__ bias,
                                               void* __restrict__ Cout, int M, int N) {
    constexpr int K = 512;
    __shared__ bf16 As[128][40];
    __shared__ bf16 Ws[128][40];
    int bid = blockIdx.x;
    int nTiles = N / 128;
    int m0 = (bid / nTiles) * 128;
    int n0 = (bid % nTiles) * 128;
    int tid = threadIdx.x;
    int wave = tid >> 6, lane = tid & 63;
    int quad = lane >> 4, l16 = lane & 15;
    int wm = (wave & 1) * 64, wn = (wave >> 1) * 64;
    f32x4 acc[4][4] = {};

    for (int k0 = 0; k0 < K; k0 += 32) {
        __syncthreads();
        #pragma unroll
        for (int r = 0; r < 2; ++r) {
            int c = tid + 256 * r;          // 0..511  (512 chunks of 8 elems per tile)
            int row = c >> 2, col = (c & 3) * 8;
            *(bf16x8*)&As[row][col] = *(const bf16x8*)&A[(size_t)(m0 + row) * K + k0 + col];
            *(bf16x8*)&Ws[row][col] = *(const bf16x8*)&W[(size_t)(n0 + row) * K + k0 + col];
        }
        __syncthreads();
        bf16x8 af[4], bfr[4];
        #pragma unroll
        for (int i = 0; i < 4; ++i) af[i] = *(const bf16x8*)&As[wm + i * 16 + l16][quad * 8];
        #pragma unroll
        for (int i = 0; i < 4; ++i) bfr[i] = *(const bf16x8*)&Ws[wn + i * 16 + l16][quad * 8];
        #pragma unroll
        for (int mt = 0; mt < 4; ++mt)
            #pragma unroll
            for (int nt = 0; nt < 4; ++nt)
                acc[mt][nt] = __builtin_amdgcn_mfma_f32_16x16x32_bf16(af[mt], bfr[nt], acc[mt][nt], 0, 0, 0);
    }

    #pragma unroll
    for (int mt = 0; mt < 4; ++mt)
        #pragma unroll
        for (int nt = 0; nt < 4; ++nt) {
            int row = m0 + wm + mt * 16 + quad * 4;
            int col = n0 + wn + nt * 16 + l16;
            float bv = bias[col];
            #pragma unroll
            for (int i = 0; i < 4; ++i) {
                float v = acc[mt][nt][i] + bv;
                if (OUT_BF16) ((bf16*)Cout)[(size_t)(row + i) * N + col] = (bf16)v;
                else          ((float*)Cout)[(size_t)(row + i) * N + col] = v;
            }
        }
}

// ---------------------------------------------------------------------------
// One LSTM timestep:
//   g[b, j] = xg[b*T+t, j] + sum_h h_in[b,h] * Wh[j,h]   (j = gate*512 + hh)
//   c = sig(f)*c + sig(i)*tanh(g) ; h = sig(o)*tanh(c)
// Block tile: 32 batch x 32 hh ; wave w computes gate w (32x32 via 2x2 MFMA).
// h ping-pong (h_in read-only, h_out write-only) avoids cross-block races.
// c_state elements are exclusively owned per block -> safe in-place.
// ---------------------------------------------------------------------------
__global__ __launch_bounds__(256) void lstm_step(const bf16* __restrict__ xg,
                                                 const bf16* __restrict__ Wh,
                                                 const bf16* __restrict__ h_in,
                                                 float* __restrict__ c_state,
                                                 bf16* __restrict__ h_out,
                                                 bf16* __restrict__ h_all, int t) {
    constexpr int K = 512, T = 128;
    __shared__ bf16 Hs[32][40];
    __shared__ bf16 Ws[4][32][40];
    __shared__ float gs[4][32][33];
    int tid = threadIdx.x;
    int b0 = (blockIdx.x >> 4) * 32;
    int n0 = (blockIdx.x & 15) * 32;
    int wave = tid >> 6, lane = tid & 63;
    int quad = lane >> 4, l16 = lane & 15;
    f32x4 acc[2][2] = {};

    for (int k0 = 0; k0 < K; k0 += 32) {
        __syncthreads();
        #pragma unroll
        for (int r = 0; r < 3; ++r) {
            int c = tid + 256 * r;          // 640 chunks total (128 Hs + 512 Ws)
            if (c < 128) {
                int row = c >> 2, col = (c & 3) * 8;
                *(bf16x8*)&Hs[row][col] = *(const bf16x8*)&h_in[(size_t)(b0 + row) * K + k0 + col];
            } else if (c < 640) {
                int c2 = c - 128;
                int g = c2 >> 7, w = c2 & 127;
                int row = w >> 2, col = (w & 3) * 8;
                *(bf16x8*)&Ws[g][row][col] =
                    *(const bf16x8*)&Wh[(size_t)(g * 512 + n0 + row) * K + k0 + col];
            }
        }
        __syncthreads();
        bf16x8 af[2], bfr[2];
        #pragma unroll
        for (int i = 0; i < 2; ++i) af[i] = *(const bf16x8*)&Hs[i * 16 + l16][quad * 8];
        #pragma unroll
        for (int i = 0; i < 2; ++i) bfr[i] = *(const bf16x8*)&Ws[wave][i * 16 + l16][quad * 8];
        #pragma unroll
        for (int mt = 0; mt < 2; ++mt)
            #pragma unroll
            for (int nt = 0; nt < 2; ++nt)
                acc[mt][nt] = __builtin_amdgcn_mfma_f32_16x16x32_bf16(af[mt], bfr[nt], acc[mt][nt], 0, 0, 0);
    }

    __syncthreads();
    #pragma unroll
    for (int mt = 0; mt < 2; ++mt)
        #pragma unroll
        for (int nt = 0; nt < 2; ++nt)
            #pragma unroll
            for (int i = 0; i < 4; ++i)
                gs[wave][mt * 16 + quad * 4 + i][nt * 16 + l16] = acc[mt][nt][i];
    __syncthreads();

    int m = tid >> 3;            // 0..31
    int nl0 = (tid & 7) * 4;     // 0,4,..,28
    int b = b0 + m;
    size_t xrow = ((size_t)b * T + t) * 2048;
    #pragma unroll
    for (int ii = 0; ii < 4; ++ii) {
        int n = nl0 + ii;
        int hh = n0 + n;
        float gi = gs[0][m][n] + (float)xg[xrow + 0 * 512 + hh];
        float gf = gs[1][m][n] + (float)xg[xrow + 1 * 512 + hh];
        float gg = gs[2][m][n] + (float)xg[xrow + 2 * 512 + hh];
        float go = gs[3][m][n] + (float)xg[xrow + 3 * 512 + hh];
        float iv = 1.f / (1.f + __expf(-gi));
        float fv = 1.f / (1.f + __expf(-gf));
        float gv = tanhf(gg);
        float ov = 1.f / (1.f + __expf(-go));
        float cp = c_state[(size_t)b * 512 + hh];
        float cn = fv * cp + iv * gv;
        float hn = ov * tanhf(cn);
        c_state[(size_t)b * 512 + hh] = cn;
        bf16 hb = (bf16)hn;
        h_out[(size_t)b * 512 + hh] = hb;
        h_all[((size_t)b * T + t) * 512 + hh] = hb;
    }
}

// ---------------------------------------------------------------------------
extern "C" void kernel_launch(void* const* d_in, const int* in_sizes, int n_in,
                              void* d_out, int out_size, void* d_ws, size_t ws_size,
                              hipStream_t stream) {
    const int*   x    = (const int*)d_in[0];
    const float* y    = (const float*)d_in[1];
    const float* emb  = (const float*)d_in[2];
    const float* yW   = (const float*)d_in[3];
    const float* yb   = (const float*)d_in[4];
    const float* Wih  = (const float*)d_in[5];
    const float* Whh  = (const float*)d_in[6];
    const float* bih  = (const float*)d_in[7];
    const float* bhh  = (const float*)d_in[8];
    const float* decW = (const float*)d_in[9];
    const float* decb = (const float*)d_in[10];
    float* out = (float*)d_out;

    char* ws = (char*)d_ws;
    size_t off = 0;
    auto alloc = [&](size_t bytes) {
        char* p = ws + off;
        off += (bytes + 255) & ~(size_t)255;
        return p;
    };
    bf16*  inp   = (bf16*)alloc(65536ull * 512 * 2);    //  64 MB (layer in/out, reused)
    bf16*  xg    = (bf16*)alloc(65536ull * 2048 * 2);   // 256 MB
    bf16*  WihB  = (bf16*)alloc(2097152ull * 2);
    bf16*  WhhB  = (bf16*)alloc(2097152ull * 2);
    bf16*  decWB = (bf16*)alloc(262144ull * 2);
    float* bias  = (float*)alloc(4096ull * 4);
    bf16*  h0buf = (bf16*)alloc(512ull * 512 * 2);
    bf16*  h1buf = (bf16*)alloc(512ull * 512 * 2);
    float* cst   = (float*)alloc(512ull * 512 * 4);

    convert_w<<<17424, 256, 0, stream>>>(Wih, Whh, decW, bih, bhh, WihB, WhhB, decWB, bias);
    prep_inp<<<16384, 256, 0, stream>>>(x, y, emb, yW, yb, inp);

    const size_t LSTRIDE = 2048ull * 512;   // per-layer weight elements (1048576)
    for (int l = 0; l < 2; ++l) {
        gemm_bt<true><<<512 * 16, 256, 0, stream>>>(inp, WihB + (size_t)l * LSTRIDE,
                                                    bias + l * 2048, xg, 65536, 2048);
        hipMemsetAsync(h0buf, 0, 512 * 512 * 2, stream);
        hipMemsetAsync(cst, 0, 512 * 512 * 4, stream);
        for (int t = 0; t < 128; ++t) {
            bf16* hin  = (t & 1) ? h1buf : h0buf;
            bf16* hout = (t & 1) ? h0buf : h1buf;
            lstm_step<<<256, 256, 0, stream>>>(xg, WhhB + (size_t)l * LSTRIDE,
                                               hin, cst, hout, inp, t);
        }
    }
    gemm_bt<false><<<512 * 4, 256, 0, stream>>>(inp, decWB, decb, out, 65536, 512);
}